// Round 8
// baseline (109.336 us; speedup 1.0000x reference)
//
#include <hip/hip_runtime.h>

// PathSampling: per node, score 32 paths (sum of centrality over masked
// prefix), stable top-8, emit selected masked paths + their edge rows.
//
// Round 8: persistent pipelined waves. Each wave owns a 14-node chunk,
// processes 2 adjacent nodes per iteration (8 independent gathers in
// flight), and prefetches the next pair's paths+lens during the current
// pair's gather/rank phase. Lane mapping as R5: lanes 0-31 carry path
// elems 0-3, lanes 32-63 elems 4-7; numpy pairwise sum preserved via one
// shfl_xor. Rank from per-wave LDS broadcast row. Intra-wave LDS only
// (program-ordered) -> no barriers anywhere.

#define N_NODE   100000
#define N_PATH   32
#define L_PATH   8
#define K_PATH   8
#define CHUNK    14   // nodes per wave; even, and N_NODE % CHUNK = 12 (even)
                      // -> a wave never sees a partially-valid pair.

typedef int   v4i __attribute__((ext_vector_type(4)));
typedef float v4f __attribute__((ext_vector_type(4)));

__global__ __launch_bounds__(256) void path_sampling_kernel(
    const int*   __restrict__ paths,
    const int*   __restrict__ edge_ids,
    const int*   __restrict__ rand_lens,
    const float* __restrict__ centrality,
    int*         __restrict__ out_paths,   // [N_NODE, K_PATH, L_PATH]
    int*         __restrict__ out_edges)   // [N_NODE, K_PATH, L_PATH-1]
{
    __shared__ float ssc[4][2][32];   // per-wave, per-pair-slot score row
    __shared__ int   wsrc[4][2][8];   // per-wave winner source path per rank

    const int t    = threadIdx.x;
    const int wv   = t >> 6;                 // wave in block (0..3)
    const int lane = t & 63;
    const int half = lane >> 5;              // 0: elems 0-3, 1: elems 4-7
    const int p    = lane & 31;              // path within node
    const int gw   = blockIdx.x * 4 + wv;    // global wave id
    const int base = gw * CHUNK;

    const v4i* P4 = (const v4i*)paths;

    // ---- prologue: load pair 0 ----
    v4i a, b;
    int la = 0, lb = 0;
    if (base < N_NODE) {
        const size_t r0 = (size_t)base * N_PATH + p;
        a  = P4[r0 * 2 + half];
        b  = P4[(r0 + N_PATH) * 2 + half];
        la = rand_lens[r0];
        lb = rand_lens[r0 + N_PATH];
    }

    for (int i = 0; i < CHUNK / 2; ++i) {
        const int n0 = base + 2 * i;
        if (n0 >= N_NODE) return;            // wave-uniform; no barriers exist
        const int n1 = n0 + 1;

        // consume current pair regs
        v4i ca4 = a, cb4 = b;
        const int lena = la, lenb = lb;

        // ---- prefetch next pair (wave-uniform condition) ----
        const int nn = n0 + 2;
        if (i + 1 < CHUNK / 2 && nn < N_NODE) {
            const size_t rn = (size_t)nn * N_PATH + p;
            a  = P4[rn * 2 + half];
            b  = P4[(rn + N_PATH) * 2 + half];
            la = rand_lens[rn];
            lb = rand_lens[rn + N_PATH];
        }

        // ---- mask both nodes, then issue all 8 gathers back-to-back ----
        const int jb = half * 4;
        int ma[4] = {ca4.x, ca4.y, ca4.z, ca4.w};
        int mb[4] = {cb4.x, cb4.y, cb4.z, cb4.w};
        #pragma unroll
        for (int k = 0; k < 4; ++k) { if (jb + k > lena) ma[k] = -1; }
        #pragma unroll
        for (int k = 0; k < 4; ++k) { if (jb + k > lenb) mb[k] = -1; }

        float ca[4], cb[4];
        #pragma unroll
        for (int k = 0; k < 4; ++k) ca[k] = (ma[k] < 0) ? 0.0f : centrality[ma[k]];
        #pragma unroll
        for (int k = 0; k < 4; ++k) cb[k] = (mb[k] < 0) ? 0.0f : centrality[mb[k]];

        // numpy pairwise tree; cross-half combine (fp add bit-commutative).
        const float psA = (ca[0] + ca[1]) + (ca[2] + ca[3]);
        const float psB = (cb[0] + cb[1]) + (cb[2] + cb[3]);
        const float sA  = psA + __shfl_xor(psA, 32);
        const float sB  = psB + __shfl_xor(psB, 32);

        // publish score rows (intra-wave LDS, program-ordered)
        if (!half) { ssc[wv][0][p] = sA; ssc[wv][1][p] = sB; }

        // ---- stable descending rank for both nodes ----
        const unsigned ltm = (1u << p) - 1u;
        int rkA = 0, rkB = 0;
        #pragma unroll
        for (int q = 0; q < 8; ++q) {
            const v4f qa = ((const v4f*)ssc[wv][0])[q];
            const v4f qb = ((const v4f*)ssc[wv][1])[q];
            #pragma unroll
            for (int e = 0; e < 4; ++e) {
                const int j = q * 4 + e;
                rkA += (qa[e] > sA) || ((qa[e] == sA) && ((ltm >> j) & 1u));
                rkB += (qb[e] > sB) || ((qb[e] == sB) && ((ltm >> j) & 1u));
            }
        }

        // ---- winner path stores + winner-row publish ----
        if (rkA < K_PATH) {
            const size_t obase = (size_t)n0 * K_PATH + rkA;
            v4i m = {ma[0], ma[1], ma[2], ma[3]};
            ((v4i*)out_paths)[obase * 2 + half] = m;
            if (!half) wsrc[wv][0][rkA] = p;
        }
        if (rkB < K_PATH) {
            const size_t obase = (size_t)n1 * K_PATH + rkB;
            v4i m = {mb[0], mb[1], mb[2], mb[3]};
            ((v4i*)out_paths)[obase * 2 + half] = m;
            if (!half) wsrc[wv][1][rkB] = p;
        }

        // ---- cooperative edge copy: 56 dwords per node, 1 ld + 1 st ----
        if (lane < 56) {
            const int r    = lane / 7;       // magic-mul
            const int col  = lane - r * 7;
            const int* e0  = edge_ids + (size_t)n0 * (N_PATH * (L_PATH - 1));
            const int* e1  = edge_ids + (size_t)n1 * (N_PATH * (L_PATH - 1));
            int* d0 = out_edges + (size_t)n0 * (K_PATH * (L_PATH - 1));
            int* d1 = out_edges + (size_t)n1 * (K_PATH * (L_PATH - 1));
            const int s0 = wsrc[wv][0][r];
            const int s1 = wsrc[wv][1][r];
            d0[lane] = e0[s0 * 7 + col];
            d1[lane] = e1[s1 * 7 + col];
        }
    }
}

extern "C" void kernel_launch(void* const* d_in, const int* in_sizes, int n_in,
                              void* d_out, int out_size, void* d_ws, size_t ws_size,
                              hipStream_t stream) {
    const int*   paths      = (const int*)  d_in[0];
    const int*   edge_ids   = (const int*)  d_in[1];
    const int*   rand_lens  = (const int*)  d_in[2];
    const float* centrality = (const float*)d_in[3];
    // d_in[4] is k_path (scalar, known == 8)

    int* out_paths = (int*)d_out;
    int* out_edges = out_paths + (size_t)N_NODE * K_PATH * L_PATH;

    // 4 waves/block, CHUNK nodes/wave -> 56 nodes/block
    const int nodes_per_block = 4 * CHUNK;
    const int grid = (N_NODE + nodes_per_block - 1) / nodes_per_block; // 1786

    path_sampling_kernel<<<grid, 256, 0, stream>>>(
        paths, edge_ids, rand_lens, centrality, out_paths, out_edges);
}

// Round 9
// 77.512 us; speedup vs baseline: 1.4106x; 1.4106x over previous
//
#include <hip/hip_runtime.h>

// PathSampling: per node, score 32 paths (sum of centrality over masked
// prefix), stable top-8, emit selected masked paths + their edge rows.
//
// Round 9: high TLP *and* high per-wave MLP. Grid 12500 x 256 (as R7's
// scale, occupancy ~67%), but each wave handles TWO adjacent nodes in
// straight-line code: 8 independent centrality gathers in flight per wave
// (4 per node via the half-split lane mapping), two LDS score rows, two
// ranks, two winner/edge copies. No persistent loop, no prefetch regs
// (R8's occupancy collapse reverted). Intra-wave LDS only -> no barriers.

#define N_NODE   100000
#define N_PATH   32
#define L_PATH   8
#define K_PATH   8

typedef int   v4i __attribute__((ext_vector_type(4)));
typedef float v4f __attribute__((ext_vector_type(4)));

__global__ __launch_bounds__(256) void path_sampling_kernel(
    const int*   __restrict__ paths,
    const int*   __restrict__ edge_ids,
    const int*   __restrict__ rand_lens,
    const float* __restrict__ centrality,
    int*         __restrict__ out_paths,   // [N_NODE, K_PATH, L_PATH]
    int*         __restrict__ out_edges)   // [N_NODE, K_PATH, L_PATH-1]
{
    __shared__ float ssc[4][2][32];   // per-wave, per-node-slot score row
    __shared__ int   wsrc[4][2][8];   // per-wave winner source path per rank

    const int t    = threadIdx.x;
    const int wv   = t >> 6;                 // wave in block (0..3)
    const int lane = t & 63;
    const int half = lane >> 5;              // 0: elems 0-3, 1: elems 4-7
    const int p    = lane & 31;              // path within node
    const int nA   = blockIdx.x * 8 + wv * 2;  // grid*8 == N_NODE exactly
    const int nB   = nA + 1;

    const size_t rA = (size_t)nA * N_PATH + p;
    const size_t rB = (size_t)nB * N_PATH + p;

    // Coalesced b128 path loads + lens for both nodes, issued together.
    const v4i* P4 = (const v4i*)paths;
    v4i a4 = P4[rA * 2 + half];
    v4i b4 = P4[rB * 2 + half];
    const int lena = rand_lens[rA];
    const int lenb = rand_lens[rB];

    // Mask both nodes, then issue all 8 gathers back-to-back.
    const int jb = half * 4;
    int ma[4] = {a4.x, a4.y, a4.z, a4.w};
    int mb[4] = {b4.x, b4.y, b4.z, b4.w};
    #pragma unroll
    for (int k = 0; k < 4; ++k) { if (jb + k > lena) ma[k] = -1; }
    #pragma unroll
    for (int k = 0; k < 4; ++k) { if (jb + k > lenb) mb[k] = -1; }

    float ca[4], cb[4];
    #pragma unroll
    for (int k = 0; k < 4; ++k) ca[k] = (ma[k] < 0) ? 0.0f : centrality[ma[k]];
    #pragma unroll
    for (int k = 0; k < 4; ++k) cb[k] = (mb[k] < 0) ? 0.0f : centrality[mb[k]];

    // numpy pairwise tree; cross-half combine (fp add is bit-commutative).
    const float psA = (ca[0] + ca[1]) + (ca[2] + ca[3]);
    const float psB = (cb[0] + cb[1]) + (cb[2] + cb[3]);
    const float sA  = psA + __shfl_xor(psA, 32);
    const float sB  = psB + __shfl_xor(psB, 32);

    // Publish both score rows (intra-wave LDS, program-ordered).
    if (!half) { ssc[wv][0][p] = sA; ssc[wv][1][p] = sB; }

    // Stable descending rank for both nodes (ties -> lower index wins).
    const unsigned ltm = (1u << p) - 1u;
    int rkA = 0, rkB = 0;
    #pragma unroll
    for (int q = 0; q < 8; ++q) {
        const v4f qa = ((const v4f*)ssc[wv][0])[q];
        const v4f qb = ((const v4f*)ssc[wv][1])[q];
        #pragma unroll
        for (int e = 0; e < 4; ++e) {
            const int j = q * 4 + e;
            rkA += (qa[e] > sA) || ((qa[e] == sA) && ((ltm >> j) & 1u));
            rkB += (qb[e] > sB) || ((qb[e] == sB) && ((ltm >> j) & 1u));
        }
    }

    // Winner path stores (16B/lane, 16 active lanes per node-slot) +
    // winner-row publish.
    if (rkA < K_PATH) {
        const size_t obase = (size_t)nA * K_PATH + rkA;
        v4i m = {ma[0], ma[1], ma[2], ma[3]};
        ((v4i*)out_paths)[obase * 2 + half] = m;
        if (!half) wsrc[wv][0][rkA] = p;
    }
    if (rkB < K_PATH) {
        const size_t obase = (size_t)nB * K_PATH + rkB;
        v4i m = {mb[0], mb[1], mb[2], mb[3]};
        ((v4i*)out_paths)[obase * 2 + half] = m;
        if (!half) wsrc[wv][1][rkB] = p;
    }

    // Cooperative edge copy: 56 dwords per node, 1 ld + 1 st per node.
    if (lane < 56) {
        const int r   = lane / 7;            // magic-mul
        const int col = lane - r * 7;
        const int* eA = edge_ids + (size_t)nA * (N_PATH * (L_PATH - 1));
        const int* eB = edge_ids + (size_t)nB * (N_PATH * (L_PATH - 1));
        int* dA = out_edges + (size_t)nA * (K_PATH * (L_PATH - 1));
        int* dB = out_edges + (size_t)nB * (K_PATH * (L_PATH - 1));
        const int s0 = wsrc[wv][0][r];
        const int s1 = wsrc[wv][1][r];
        dA[lane] = eA[s0 * 7 + col];
        dB[lane] = eB[s1 * 7 + col];
    }
}

extern "C" void kernel_launch(void* const* d_in, const int* in_sizes, int n_in,
                              void* d_out, int out_size, void* d_ws, size_t ws_size,
                              hipStream_t stream) {
    const int*   paths      = (const int*)  d_in[0];
    const int*   edge_ids   = (const int*)  d_in[1];
    const int*   rand_lens  = (const int*)  d_in[2];
    const float* centrality = (const float*)d_in[3];
    // d_in[4] is k_path (scalar, known == 8)

    int* out_paths = (int*)d_out;
    int* out_edges = out_paths + (size_t)N_NODE * K_PATH * L_PATH;

    // 4 waves/block x 2 nodes/wave = 8 nodes/block
    const int grid = N_NODE / 8;             // 12500, exact

    path_sampling_kernel<<<grid, 256, 0, stream>>>(
        paths, edge_ids, rand_lens, centrality, out_paths, out_edges);
}

// Round 10
// 73.772 us; speedup vs baseline: 1.4821x; 1.0507x over previous
//
#include <hip/hip_runtime.h>

// PathSampling: per node, score 32 paths (sum of centrality over masked
// prefix), stable top-8, emit selected masked paths + their edge rows.
//
// Round 10: R9 structure + NON-TEMPORAL STORES ONLY. Outputs (48 MB) are
// write-only and were evicting the 217.6 MB input set from the 256 MB
// Infinity Cache between graph replays (inputs+outputs = 265.6 MB > L3).
// NT stores keep outputs out of L3 so inputs stay resident across replays.
// (R3 showed NT on LOADS kills input reuse -> +35us; this isolates the
// store half.) Loads remain plain/cached.

#define N_NODE   100000
#define N_PATH   32
#define L_PATH   8
#define K_PATH   8

typedef int   v4i __attribute__((ext_vector_type(4)));
typedef float v4f __attribute__((ext_vector_type(4)));

__global__ __launch_bounds__(256) void path_sampling_kernel(
    const int*   __restrict__ paths,
    const int*   __restrict__ edge_ids,
    const int*   __restrict__ rand_lens,
    const float* __restrict__ centrality,
    int*         __restrict__ out_paths,   // [N_NODE, K_PATH, L_PATH]
    int*         __restrict__ out_edges)   // [N_NODE, K_PATH, L_PATH-1]
{
    __shared__ float ssc[4][2][32];   // per-wave, per-node-slot score row
    __shared__ int   wsrc[4][2][8];   // per-wave winner source path per rank

    const int t    = threadIdx.x;
    const int wv   = t >> 6;                 // wave in block (0..3)
    const int lane = t & 63;
    const int half = lane >> 5;              // 0: elems 0-3, 1: elems 4-7
    const int p    = lane & 31;              // path within node
    const int nA   = blockIdx.x * 8 + wv * 2;  // grid*8 == N_NODE exactly
    const int nB   = nA + 1;

    const size_t rA = (size_t)nA * N_PATH + p;
    const size_t rB = (size_t)nB * N_PATH + p;

    // Coalesced b128 path loads + lens for both nodes, issued together.
    const v4i* P4 = (const v4i*)paths;
    v4i a4 = P4[rA * 2 + half];
    v4i b4 = P4[rB * 2 + half];
    const int lena = rand_lens[rA];
    const int lenb = rand_lens[rB];

    // Mask both nodes, then issue all 8 gathers back-to-back.
    const int jb = half * 4;
    int ma[4] = {a4.x, a4.y, a4.z, a4.w};
    int mb[4] = {b4.x, b4.y, b4.z, b4.w};
    #pragma unroll
    for (int k = 0; k < 4; ++k) { if (jb + k > lena) ma[k] = -1; }
    #pragma unroll
    for (int k = 0; k < 4; ++k) { if (jb + k > lenb) mb[k] = -1; }

    float ca[4], cb[4];
    #pragma unroll
    for (int k = 0; k < 4; ++k) ca[k] = (ma[k] < 0) ? 0.0f : centrality[ma[k]];
    #pragma unroll
    for (int k = 0; k < 4; ++k) cb[k] = (mb[k] < 0) ? 0.0f : centrality[mb[k]];

    // numpy pairwise tree; cross-half combine (fp add is bit-commutative).
    const float psA = (ca[0] + ca[1]) + (ca[2] + ca[3]);
    const float psB = (cb[0] + cb[1]) + (cb[2] + cb[3]);
    const float sA  = psA + __shfl_xor(psA, 32);
    const float sB  = psB + __shfl_xor(psB, 32);

    // Publish both score rows (intra-wave LDS, program-ordered).
    if (!half) { ssc[wv][0][p] = sA; ssc[wv][1][p] = sB; }

    // Stable descending rank for both nodes (ties -> lower index wins).
    const unsigned ltm = (1u << p) - 1u;
    int rkA = 0, rkB = 0;
    #pragma unroll
    for (int q = 0; q < 8; ++q) {
        const v4f qa = ((const v4f*)ssc[wv][0])[q];
        const v4f qb = ((const v4f*)ssc[wv][1])[q];
        #pragma unroll
        for (int e = 0; e < 4; ++e) {
            const int j = q * 4 + e;
            rkA += (qa[e] > sA) || ((qa[e] == sA) && ((ltm >> j) & 1u));
            rkB += (qb[e] > sB) || ((qb[e] == sB) && ((ltm >> j) & 1u));
        }
    }

    // Winner path stores: NT (write-only output, keep out of L3).
    if (rkA < K_PATH) {
        const size_t obase = (size_t)nA * K_PATH + rkA;
        v4i m = {ma[0], ma[1], ma[2], ma[3]};
        __builtin_nontemporal_store(m, ((v4i*)out_paths) + obase * 2 + half);
        if (!half) wsrc[wv][0][rkA] = p;
    }
    if (rkB < K_PATH) {
        const size_t obase = (size_t)nB * K_PATH + rkB;
        v4i m = {mb[0], mb[1], mb[2], mb[3]};
        __builtin_nontemporal_store(m, ((v4i*)out_paths) + obase * 2 + half);
        if (!half) wsrc[wv][1][rkB] = p;
    }

    // Cooperative edge copy: 56 dwords per node; loads cached (inputs),
    // stores NT (write-only output).
    if (lane < 56) {
        const int r   = lane / 7;            // magic-mul
        const int col = lane - r * 7;
        const int* eA = edge_ids + (size_t)nA * (N_PATH * (L_PATH - 1));
        const int* eB = edge_ids + (size_t)nB * (N_PATH * (L_PATH - 1));
        int* dA = out_edges + (size_t)nA * (K_PATH * (L_PATH - 1));
        int* dB = out_edges + (size_t)nB * (K_PATH * (L_PATH - 1));
        const int s0 = wsrc[wv][0][r];
        const int s1 = wsrc[wv][1][r];
        __builtin_nontemporal_store(eA[s0 * 7 + col], dA + lane);
        __builtin_nontemporal_store(eB[s1 * 7 + col], dB + lane);
    }
}

extern "C" void kernel_launch(void* const* d_in, const int* in_sizes, int n_in,
                              void* d_out, int out_size, void* d_ws, size_t ws_size,
                              hipStream_t stream) {
    const int*   paths      = (const int*)  d_in[0];
    const int*   edge_ids   = (const int*)  d_in[1];
    const int*   rand_lens  = (const int*)  d_in[2];
    const float* centrality = (const float*)d_in[3];
    // d_in[4] is k_path (scalar, known == 8)

    int* out_paths = (int*)d_out;
    int* out_edges = out_paths + (size_t)N_NODE * K_PATH * L_PATH;

    // 4 waves/block x 2 nodes/wave = 8 nodes/block
    const int grid = N_NODE / 8;             // 12500, exact

    path_sampling_kernel<<<grid, 256, 0, stream>>>(
        paths, edge_ids, rand_lens, centrality, out_paths, out_edges);
}